// Round 5
// baseline (180.016 us; speedup 1.0000x reference)
//
#include <hip/hip_runtime.h>
#include <math.h>

// ---------------------------------------------------------------------------
// Problem: B=4, N=2048, D=256.
// Key exact simplifications:
//  * intra+inter == 1  -> attention = softmax_j(leaky_relu(s1_i + s2_j)), no masks
//  * rank-1 + monotone -> h_prime via sorted-s2 prefix sums (O(N D), exact)
//  * evt / k_base / w_i / w_o folded into matvecs; only 3 big GEMMs remain
// R1: k_hprime -> k_rank + k_hprime2 (was 73us latency-bound).
// R2: k_setup -> k_qpart + k_qfinish + k_rowdots (was 64us, 4 blocks).
// R3: f32 VALU GEMMs -> bf16 MFMA 16x16x32 (3x40us -> ~8us each).
// R4: critical-path surgery: bitonic k_sort -> k_cntj (rank-by-count) + k_scan;
//     f32->bf16 folded into MFMA staging (k_cvt + bf16 copies gone);
//     k_logits fused into k_hprime2; k_p2 folded into k_p3; tail GEMMs merged
//     into one dispatch (blockIdx.z). 19 -> 16 dispatches.
// ---------------------------------------------------------------------------

namespace {
constexpr int B = 4, N = 2048, D = 256;
constexpr float ALPHA = 0.2f;
constexpr float INVS  = 0.0625f;   // 1/sqrt(256)

// ws offsets (float elements)
constexpr size_t OFF_H     = 0;                       // (B,N,D)
constexpr size_t OFF_HP    = 2097152;                 // h_prime
constexpr size_t OFF_UE    = 4194304;                 // u_emo
constexpr size_t OFF_UA    = 6291456;                 // u_act
constexpr size_t OFF_PPOS  = 8388608;                 // (B,N+1,D) prefix, later Ve
constexpr size_t OFF_PNEG  = 10486784;                // (B,N+1,D) prefix, later Va
constexpr size_t OFF_VE    = OFF_PPOS;
constexpr size_t OFF_VA    = OFF_PNEG;
constexpr size_t OFF_S1    = 12584960;                // (B,N)
constexpr size_t OFF_S2    = OFF_S1 + 8192;
constexpr size_t OFF_SV    = OFF_S2 + 8192;           // sorted s2
constexpr size_t OFF_SIDX  = OFF_SV + 8192;           // permutation (int)
constexpr size_t OFF_WP    = OFF_SIDX + 8192;         // e^{s2} sorted
constexpr size_t OFF_WN    = OFF_WP + 8192;           // e^{a s2} sorted
constexpr size_t OFF_ZP    = OFF_WN + 8192;           // (B,N+1) scalar prefix
constexpr size_t OFF_ZN    = OFF_ZP + 8196;
constexpr size_t OFF_PARTP = OFF_ZN + 8196;           // (B,32,D) chunk partials
constexpr size_t OFF_PARTN = OFF_PARTP + 32768;
constexpr size_t OFF_LE    = OFF_PARTN + 32768;       // emo logits
constexpr size_t OFF_LA    = OFF_LE + 8192;           // act logits
constexpr size_t OFF_SET   = OFF_LA + 8192;
constexpr size_t KQE = OFF_SET + 0;      // kW@q per batch (B,256)
constexpr size_t WQE = OFF_SET + 1024;
constexpr size_t KQA = OFF_SET + 2048;
constexpr size_t WQA = OFF_SET + 3072;
constexpr size_t QCE = OFF_SET + 4096;   // q + vb + wb
constexpr size_t QCA = OFF_SET + 5120;
constexpr size_t CA2 = OFF_SET + 6144;   // csk_W @ a2 (256)
constexpr size_t CEc = OFF_SET + 6400;   // q.(kb+wb) per batch
constexpr size_t CAc = OFF_SET + 6404;
constexpr size_t C2c = OFF_SET + 6408;   // 2*csk_b.a2
constexpr size_t OFF_RNK   = OFF_SET + 8192;          // (B,N) int
constexpr size_t OFF_C0    = OFF_RNK + 8192;          // ep/den
constexpr size_t OFF_C1    = OFF_C0 + 8192;           // en/den
constexpr size_t OFF_PARTQ = OFF_C1 + 8192;           // [m2][c16][b4][256]
constexpr size_t OFF_QE    = OFF_PARTQ + 32768;       // (B,256)
constexpr size_t OFF_QA    = OFF_QE + 1024;
constexpr size_t OFF_BT    = OFF_QA + 1024;           // 5 x 256x256 bf16 B^T (ushort)
}

typedef __attribute__((ext_vector_type(8))) short bf16x8;
typedef __attribute__((ext_vector_type(4))) float f32x4;

__device__ inline float wave_sum(float v) {
#pragma unroll
  for (int off = 32; off > 0; off >>= 1) v += __shfl_xor(v, off, 64);
  return v;
}

__device__ inline ushort f2bf(float x) {
  union { float f; uint u; } v; v.f = x;
  return (ushort)((v.u + 0x7FFFu + ((v.u >> 16) & 1u)) >> 16);
}
__device__ inline uint pk2bf(float a, float b) {
  return (uint)f2bf(a) | ((uint)f2bf(b) << 16);
}

// --- R3: transpose + convert the 5 weight matrices (256x256) ------------------
__global__ __launch_bounds__(256) void k_bt(
    const float* __restrict__ Wm, const float* __restrict__ eW,
    const float* __restrict__ aW, ushort* __restrict__ bt)
{
  int m = blockIdx.y;
  const float* src = (m == 0) ? Wm : (m == 1) ? eW + 3*65536 : (m == 2) ? eW
                   : (m == 3) ? aW + 3*65536 : aW;
  ushort* dst = bt + (size_t)m*65536;
  int k0 = (blockIdx.x >> 2)*64, n0 = (blockIdx.x & 3)*64;
  __shared__ float tile[64][65];
  int r = threadIdx.x >> 2, c0 = (threadIdx.x & 3)*16;
#pragma unroll
  for (int cc = 0; cc < 16; cc += 4)
    *(float4*)&tile[r][c0+cc] = *(const float4*)&src[(size_t)(k0+r)*256 + n0 + c0 + cc];
  __syncthreads();
  int n = threadIdx.x >> 2, kq = (threadIdx.x & 3)*16;
  uint4 o0, o1;
  o0.x = pk2bf(tile[kq+ 0][n], tile[kq+ 1][n]);
  o0.y = pk2bf(tile[kq+ 2][n], tile[kq+ 3][n]);
  o0.z = pk2bf(tile[kq+ 4][n], tile[kq+ 5][n]);
  o0.w = pk2bf(tile[kq+ 6][n], tile[kq+ 7][n]);
  o1.x = pk2bf(tile[kq+ 8][n], tile[kq+ 9][n]);
  o1.y = pk2bf(tile[kq+10][n], tile[kq+11][n]);
  o1.z = pk2bf(tile[kq+12][n], tile[kq+13][n]);
  o1.w = pk2bf(tile[kq+14][n], tile[kq+15][n]);
  *(uint4*)&dst[(size_t)(n0+n)*256 + k0 + kq]     = o0;
  *(uint4*)&dst[(size_t)(n0+n)*256 + k0 + kq + 8] = o1;
}

// --- R4: MFMA body with inline f32->bf16 A staging ----------------------------
// A: f32 row-major (8192,256). B: bf16 pre-transposed (N rows, K cols).
// BM=64, BN=128, BK=32; 4 waves (2M x 2N); per wave 2x4 16x16 frags.
__device__ __forceinline__ void mgemm_body(ushort* As,
    const float* __restrict__ A1, const ushort* __restrict__ B1,
    const float* __restrict__ A2, const ushort* __restrict__ B2,
    float* __restrict__ C)
{
  const int t = threadIdx.x;
  const int lane = t & 63, w = t >> 6;
  const int wm = w >> 1, wn = w & 1;
  const int laneN = lane & 15, kg = lane >> 4;
  const int m0 = blockIdx.x * 64, n0 = blockIdx.y * 128;
  const int srow = t >> 2, sq = t & 3;
  f32x4 acc[2][4] = {};
  for (int src = 0; src < 2; ++src) {
    const float* A = src ? A2 : A1;
    const ushort* Bt = src ? B2 : B1;
    if (!A) break;
    for (int k0 = 0; k0 < 256; k0 += 32) {
      __syncthreads();
      float4 f0 = *(const float4*)&A[(size_t)(m0 + srow)*256 + k0 + sq*8];
      float4 f1 = *(const float4*)&A[(size_t)(m0 + srow)*256 + k0 + sq*8 + 4];
      uint4 o;
      o.x = pk2bf(f0.x, f0.y); o.y = pk2bf(f0.z, f0.w);
      o.z = pk2bf(f1.x, f1.y); o.w = pk2bf(f1.z, f1.w);
      *(uint4*)&As[srow*40 + sq*8] = o;
      __syncthreads();
      bf16x8 bf[4];
#pragma unroll
      for (int j = 0; j < 4; ++j)
        bf[j] = *(const bf16x8*)&Bt[(size_t)(n0 + wn*64 + j*16 + laneN)*256 + k0 + kg*8];
#pragma unroll
      for (int i = 0; i < 2; ++i) {
        bf16x8 af = *(const bf16x8*)&As[(wm*32 + i*16 + laneN)*40 + kg*8];
#pragma unroll
        for (int j = 0; j < 4; ++j)
          acc[i][j] = __builtin_amdgcn_mfma_f32_16x16x32_bf16(af, bf[j], acc[i][j], 0, 0, 0);
      }
    }
  }
#pragma unroll
  for (int i = 0; i < 2; ++i)
#pragma unroll
    for (int j = 0; j < 4; ++j)
#pragma unroll
      for (int r = 0; r < 4; ++r)
        C[(size_t)(m0 + wm*32 + i*16 + kg*4 + r)*256 + n0 + wn*64 + j*16 + laneN]
            = acc[i][j][r];
}

__global__ __launch_bounds__(256) void k_mgemmh(
    const float* __restrict__ A1, const ushort* __restrict__ bt,
    float* __restrict__ C)
{
  __shared__ ushort As[64*40];
  mgemm_body(As, A1, bt, nullptr, nullptr, C);
}

// z=0: Ve = hp@eW_v + ue@eW_w ; z=1: Va = hp@aW_v + ua@aW_w
__global__ __launch_bounds__(256) void k_mgemm2(
    const float* __restrict__ hp, const ushort* __restrict__ bt,
    float* __restrict__ ws)
{
  __shared__ ushort As[64*40];
  int z = blockIdx.z;
  const float* A2 = ws + (z ? OFF_UA : OFF_UE);
  const ushort* B1 = bt + (size_t)(z ? 3 : 1)*65536;
  const ushort* B2 = bt + (size_t)(z ? 4 : 2)*65536;
  float* C = ws + (z ? OFF_VA : OFF_VE);
  mgemm_body(As, hp, B1, A2, B2, C);
}

// --- R2: split-k partials of q = x @ qW ---------------------------------------
__global__ __launch_bounds__(256) void k_qpart(
    const float* __restrict__ inp, const float* __restrict__ emo,
    const float* __restrict__ eW, const float* __restrict__ aW,
    const int* __restrict__ cl, float* __restrict__ ws)
{
  int c = blockIdx.x;          // k-chunk 0..15
  int m = blockIdx.y;          // 0=emo, 1=act
  int d = threadIdx.x;
  __shared__ float xs[B][16];
  if (d < 64) {
    int b = d >> 4, kk = d & 15;
    int t = cl[b] - 1;
    size_t idx = ((size_t)b*N + t)*D + c*16 + kk;
    float v = inp[idx];
    if (m == 0) v += emo[idx];
    xs[b][kk] = v;
  }
  __syncthreads();
  const float* Wq = (m ? aW : eW) + (size_t)D*D;   // lin_W[1]
  float acc0 = 0.f, acc1 = 0.f, acc2 = 0.f, acc3 = 0.f;
#pragma unroll
  for (int kk = 0; kk < 16; ++kk) {
    int k = c*16 + kk;
    float w = Wq[(size_t)k*D + d];
    acc0 += xs[0][kk]*w; acc1 += xs[1][kk]*w;
    acc2 += xs[2][kk]*w; acc3 += xs[3][kk]*w;
  }
  size_t base = OFF_PARTQ + ((size_t)(m*16 + c)*4)*256 + d;
  ws[base + 0*256] = acc0; ws[base + 1*256] = acc1;
  ws[base + 2*256] = acc2; ws[base + 3*256] = acc3;
}

// --- R2: q = sum partials + qb; qc; scalar dots --------------------------------
__global__ __launch_bounds__(256) void k_qfinish(
    const float* __restrict__ eb, const float* __restrict__ ab,
    const float* __restrict__ cskb, const float* __restrict__ a,
    float* __restrict__ ws)
{
  int b = blockIdx.x, m = blockIdx.y, d = threadIdx.x;
  __shared__ float red[D];
  const float* bias = m ? ab : eb;
  float q = bias[D + d];
#pragma unroll
  for (int c = 0; c < 16; ++c)
    q += ws[OFF_PARTQ + ((size_t)(m*16 + c)*4 + b)*256 + d];
  ws[(m ? OFF_QA : OFF_QE) + (size_t)b*D + d] = q;
  ws[(m ? QCA : QCE) + (size_t)b*D + d] = q + bias[3*D + d] + bias[0*D + d];
  red[d] = q * (bias[2*D + d] + bias[0*D + d]);
  __syncthreads();
  for (int s = 128; s > 0; s >>= 1) { if (d < s) red[d] += red[d+s]; __syncthreads(); }
  if (d == 0) ws[(m ? CAc : CEc) + b] = red[0];
  if (m == 1 && b == 0) {
    __syncthreads();
    red[d] = cskb[d] * a[D + d];
    __syncthreads();
    for (int s = 128; s > 0; s >>= 1) { if (d < s) red[d] += red[d+s]; __syncthreads(); }
    if (d == 0) ws[C2c] = 2.0f * red[0];
  }
}

// --- R2: 17 row-major matvecs, wave-per-row, coalesced -------------------------
__global__ __launch_bounds__(256) void k_rowdots(
    const float* __restrict__ eW, const float* __restrict__ aW,
    const float* __restrict__ cskW, const float* __restrict__ a,
    float* __restrict__ ws)
{
  int job = blockIdx.y;
  int wid = threadIdx.x >> 6, lane = threadIdx.x & 63;
  int row = blockIdx.x*4 + wid;
  __shared__ float vec[D];
  const float* M; size_t outo;
  if (job < 16) {
    int b = job >> 2, m = (job >> 1) & 1, which = job & 1;
    const float* base = m ? aW : eW;
    M = base + (which ? 0 : (size_t)2*D*D);          // wW : kW
    if (threadIdx.x < D)
      vec[threadIdx.x] = ws[(m ? OFF_QA : OFF_QE) + (size_t)b*D + threadIdx.x];
    outo = (which ? (m ? WQA : WQE) : (m ? KQA : KQE)) + (size_t)b*D;
  } else {
    M = cskW;
    if (threadIdx.x < D) vec[threadIdx.x] = a[D + threadIdx.x];
    outo = CA2;
  }
  __syncthreads();
  float4 w = *reinterpret_cast<const float4*>(&M[(size_t)row*D + lane*4]);
  float s = w.x*vec[lane*4] + w.y*vec[lane*4+1] + w.z*vec[lane*4+2] + w.w*vec[lane*4+3];
  s = wave_sum(s);
  if (lane == 0) ws[outo + row] = s;
}

// --- u = tim*icsk + (1-tim)*ocsk for both measures ----------------------------
__global__ __launch_bounds__(256) void k_u(
    const float* __restrict__ ei, const float* __restrict__ eo,
    const float* __restrict__ ai, const float* __restrict__ ao,
    const int* __restrict__ cl, const int* __restrict__ intra,
    float* __restrict__ ws)
{
  size_t g = (size_t)blockIdx.x*256 + threadIdx.x;
  size_t base = g << 2;
  int b = (int)(base >> 19);              // N*D = 2^19
  int n = (int)((base >> 8) & (N - 1));
  int t = cl[b] - 1;
  float tm = (float)intra[(size_t)b*N*N + (size_t)t*N + n];
  float om = 1.0f - tm;
  float4 vei = *(const float4*)&ei[base];
  float4 veo = *(const float4*)&eo[base];
  float4 vai = *(const float4*)&ai[base];
  float4 vao = *(const float4*)&ao[base];
  float4 ue, ua;
  ue.x = tm*vei.x + om*veo.x; ue.y = tm*vei.y + om*veo.y;
  ue.z = tm*vei.z + om*veo.z; ue.w = tm*vei.w + om*veo.w;
  ua.x = tm*vai.x + om*vao.x; ua.y = tm*vai.y + om*vao.y;
  ua.z = tm*vai.z + om*vao.z; ua.w = tm*vai.w + om*vao.w;
  *(float4*)&ws[OFF_UE + base] = ue;
  *(float4*)&ws[OFF_UA + base] = ua;
}

// --- s1 = h.a1 ; s2 = h.a2 + (bef+aft).ca2 + c2 -------------------------------
__global__ __launch_bounds__(256) void k_s12(
    const float* __restrict__ bef, const float* __restrict__ aft,
    const float* __restrict__ a, float* __restrict__ ws)
{
  int wid  = (int)(((size_t)blockIdx.x*256 + threadIdx.x) >> 6);
  int lane = threadIdx.x & 63;
  int d0 = lane << 2;
  float4 a1 = *(const float4*)&a[d0];
  float4 a2 = *(const float4*)&a[D + d0];
  float4 cv = *(const float4*)&ws[CA2 + d0];
  float c2  = ws[C2c];
  for (int rr = 0; rr < 4; ++rr) {
    int row = wid*4 + rr;
    float4 h4 = *(const float4*)&ws[OFF_H + (size_t)row*D + d0];
    float4 b4 = *(const float4*)&bef[(size_t)row*D + d0];
    float4 f4 = *(const float4*)&aft[(size_t)row*D + d0];
    float s1 = h4.x*a1.x + h4.y*a1.y + h4.z*a1.z + h4.w*a1.w;
    float s2 = h4.x*a2.x + h4.y*a2.y + h4.z*a2.z + h4.w*a2.w
             + (b4.x+f4.x)*cv.x + (b4.y+f4.y)*cv.y
             + (b4.z+f4.z)*cv.z + (b4.w+f4.w)*cv.w;
    s1 = wave_sum(s1); s2 = wave_sum(s2);
    if (lane == 0) { ws[OFF_S1 + row] = s1; ws[OFF_S2 + row] = s2 + c2; }
  }
}

// --- R4: rank-by-count sort replacement; scatters sorted SV/SIDX/WP/WN --------
__global__ __launch_bounds__(256) void k_cntj(float* __restrict__ ws)
{
  int b = blockIdx.y;
  int j = blockIdx.x * 256 + threadIdx.x;
  __shared__ float s2s[N];
  for (int r = threadIdx.x; r < N; r += 256)
    s2s[r] = ws[OFF_S2 + (size_t)b*N + r];
  __syncthreads();
  float v = s2s[j];
  int cnt = 0;
  for (int k = 0; k < N; k += 4) {
    float4 u = *(const float4*)&s2s[k];
    cnt += (u.x < v) || (u.x == v && (k+0) < j);
    cnt += (u.y < v) || (u.y == v && (k+1) < j);
    cnt += (u.z < v) || (u.z == v && (k+2) < j);
    cnt += (u.w < v) || (u.w == v && (k+3) < j);
  }
  size_t o = (size_t)b*N + cnt;
  ws[OFF_SV + o] = v;
  ((int*)ws)[OFF_SIDX + o] = j;
  ws[OFF_WP + o] = expf(v);
  ws[OFF_WN + o] = expf(ALPHA*v);
}

// --- R4: scalar prefix sums of sorted WP/WN -> ZP/ZN ---------------------------
__global__ __launch_bounds__(1024) void k_scan(float* __restrict__ ws)
{
  int b = blockIdx.x, m = blockIdx.y, t = threadIdx.x;
  const float* src = ws + (m ? OFF_WN : OFF_WP) + (size_t)b*N;
  float* dst = ws + (m ? OFF_ZN : OFF_ZP) + (size_t)b*(N+1);
  __shared__ float buf[N];
  buf[t] = src[t]; buf[t + 1024] = src[t + 1024];
  __syncthreads();
  for (int off = 1; off < N; off <<= 1) {
    float v0 = (t >= off)        ? buf[t - off]        : 0.f;
    float v1 = (t + 1024 >= off) ? buf[t + 1024 - off] : 0.f;
    __syncthreads();
    buf[t] += v0; buf[t + 1024] += v1;
    __syncthreads();
  }
  if (t == 0) dst[0] = 0.f;
  dst[t + 1]    = buf[t];
  dst[t + 1025] = buf[t + 1024];
}

// --- R1: per-row rank + folded softmax coefficients ----------------------------
__global__ __launch_bounds__(256) void k_rank(float* __restrict__ ws)
{
  int b = blockIdx.y;
  int i = blockIdx.x * 256 + threadIdx.x;
  __shared__ float sv[N];
  for (int r = threadIdx.x; r < N; r += 256) sv[r] = ws[OFF_SV + (size_t)b*N + r];
  __syncthreads();
  float s1i = ws[OFF_S1 + (size_t)b*N + i];
  float th = -s1i;
  int lo = 0, hi = N;
  while (lo < hi) { int mid = (lo + hi) >> 1; if (sv[mid] <= th) lo = mid + 1; else hi = mid; }
  int r = lo;
  float ep = expf(s1i), en = expf(ALPHA*s1i);
  float zp  = ws[OFF_ZP + (size_t)b*(N+1) + r];
  float zn  = ws[OFF_ZN + (size_t)b*(N+1) + r];
  float zpT = ws[OFF_ZP + (size_t)b*(N+1) + N];
  float den = ep*(zpT - zp) + en*zn;
  ((int*)ws)[OFF_RNK + (size_t)b*N + i] = r;
  ws[OFF_C0 + (size_t)b*N + i] = ep/den;
  ws[OFF_C1 + (size_t)b*N + i] = en/den;
}

// --- vector partials over sorted order ----------------------------------------
__global__ __launch_bounds__(256) void k_p1(float* __restrict__ ws)
{
  int c = blockIdx.x, b = blockIdx.y, d = threadIdx.x;
  const int*   sidx = (const int*)ws + OFF_SIDX + (size_t)b*N;
  const float* wp = ws + OFF_WP + (size_t)b*N;
  const float* wn = ws + OFF_WN + (size_t)b*N;
  const float* h  = ws + OFF_H + (size_t)b*N*D;
  float ap = 0.f, an = 0.f;
  for (int r = c*64; r < c*64 + 64; ++r) {
    float hv = h[(size_t)sidx[r]*D + d];
    ap += wp[r]*hv; an += wn[r]*hv;
  }
  ws[OFF_PARTP + ((size_t)b*32 + c)*D + d] = ap;
  ws[OFF_PARTN + ((size_t)b*32 + c)*D + d] = an;
}

// --- R4: p3 computes its own chunk offset (k_p2 removed) -----------------------
__global__ __launch_bounds__(256) void k_p3(float* __restrict__ ws)
{
  int c = blockIdx.x, b = blockIdx.y, d = threadIdx.x;
  const int*   sidx = (const int*)ws + OFF_SIDX + (size_t)b*N;
  const float* wp = ws + OFF_WP + (size_t)b*N;
  const float* wn = ws + OFF_WN + (size_t)b*N;
  const float* h  = ws + OFF_H + (size_t)b*N*D;
  float ap = 0.f, an = 0.f;
  for (int c2 = 0; c2 < c; ++c2) {
    ap += ws[OFF_PARTP + ((size_t)b*32 + c2)*D + d];
    an += ws[OFF_PARTN + ((size_t)b*32 + c2)*D + d];
  }
  for (int r = c*64; r < c*64 + 64; ++r) {
    ws[OFF_PPOS + ((size_t)b*(N+1) + r)*D + d] = ap;
    ws[OFF_PNEG + ((size_t)b*(N+1) + r)*D + d] = an;
    float hv = h[(size_t)sidx[r]*D + d];
    ap += wp[r]*hv; an += wn[r]*hv;
  }
  if (c == 31) {
    ws[OFF_PPOS + ((size_t)b*(N+1) + N)*D + d] = ap;
    ws[OFF_PNEG + ((size_t)b*(N+1) + N)*D + d] = an;
  }
}

// --- R4: h_prime gather + fused logits (k_logits removed) ----------------------
__global__ __launch_bounds__(256) void k_hprime2(float* __restrict__ ws)
{
  int b = blockIdx.y, d = threadIdx.x;
  int i0 = blockIdx.x * 8;
  float totp = ws[OFF_PPOS + ((size_t)b*(N+1) + N)*D + d];
  float kqe = ws[KQE + (size_t)b*D + d], wqe = ws[WQE + (size_t)b*D + d];
  float kqa = ws[KQA + (size_t)b*D + d], wqa = ws[WQA + (size_t)b*D + d];
  float se[8], sa[8];
#pragma unroll
  for (int ii = 0; ii < 8; ++ii) {
    int i = i0 + ii;
    int   r  = ((const int*)ws)[OFF_RNK + (size_t)b*N + i];
    float c0 = ws[OFF_C0 + (size_t)b*N + i];
    float c1 = ws[OFF_C1 + (size_t)b*N + i];
    float pp = ws[OFF_PPOS + ((size_t)b*(N+1) + r)*D + d];
    float pn = ws[OFF_PNEG + ((size_t)b*(N+1) + r)*D + d];
    float v = c0*(totp - pp) + c1*pn;
    size_t base = ((size_t)b*N + i)*D + d;
    ws[OFF_HP + base] = v;
    float ue = ws[OFF_UE + base], ua = ws[OFF_UA + base];
    se[ii] = v*kqe + ue*wqe;
    sa[ii] = v*kqa + ua*wqa;
  }
  __shared__ float lred[16][4];
  int w = d >> 6, lane = d & 63;
#pragma unroll
  for (int ii = 0; ii < 8; ++ii) {
    float s = wave_sum(se[ii]);
    if (lane == 0) lred[ii][w] = s;
    s = wave_sum(sa[ii]);
    if (lane == 0) lred[8 + ii][w] = s;
  }
  __syncthreads();
  if (d < 16) {
    float s = lred[d][0] + lred[d][1] + lred[d][2] + lred[d][3];
    size_t row = (size_t)b*N + i0 + (d & 7);
    if (d < 8) ws[OFF_LE + row] = (s + ws[CEc + b]) * INVS;
    else       ws[OFF_LA + row] = (s + ws[CAc + b]) * INVS;
  }
}

// --- probs softmax over N, writes directly to d_out -----------------------------
__global__ __launch_bounds__(1024) void k_softmax(const float* __restrict__ ws,
                                                  float* __restrict__ out)
{
  int b = blockIdx.x, t = threadIdx.x;
  __shared__ float red[1024];
  for (int m = 0; m < 2; ++m) {
    const float* l = ws + (m ? OFF_LA : OFF_LE) + (size_t)b*N;
    float* p = out + (size_t)B*N*D + (size_t)m*B*N + (size_t)b*N;
    float v0 = l[t], v1 = l[t + 1024];
    red[t] = fmaxf(v0, v1);
    __syncthreads();
    for (int s = 512; s > 0; s >>= 1) { if (t < s) red[t] = fmaxf(red[t], red[t+s]); __syncthreads(); }
    float mx = red[0];
    __syncthreads();
    float e0 = expf(v0 - mx), e1 = expf(v1 - mx);
    red[t] = e0 + e1;
    __syncthreads();
    for (int s = 512; s > 0; s >>= 1) { if (t < s) red[t] += red[t+s]; __syncthreads(); }
    float inv = 1.0f / red[0];
    __syncthreads();
    p[t] = e0 * inv; p[t + 1024] = e1 * inv;
    __syncthreads();
  }
}

// --- final: out = relu(h' + inp + pe*(qce+Ve) + pa*(qca+Va)) --------------------
__global__ __launch_bounds__(256) void k_final(
    const float* __restrict__ inp, const float* __restrict__ ws,
    float* __restrict__ out)
{
  size_t g = (size_t)blockIdx.x*256 + threadIdx.x;
  size_t base = g << 2;
  int b  = (int)(base >> 19);
  int n  = (int)((base >> 8) & (N - 1));
  int d0 = (int)(base & (D - 1));
  float pe = out[(size_t)B*N*D + (size_t)b*N + n];
  float pa = out[(size_t)B*N*D + (size_t)B*N + (size_t)b*N + n];
  float4 hp = *(const float4*)&ws[OFF_HP + base];
  float4 iv = *(const float4*)&inp[base];
  float4 ve = *(const float4*)&ws[OFF_VE + base];
  float4 va = *(const float4*)&ws[OFF_VA + base];
  float4 qe = *(const float4*)&ws[QCE + (size_t)b*D + d0];
  float4 qa = *(const float4*)&ws[QCA + (size_t)b*D + d0];
  float4 o;
  o.x = hp.x + iv.x + pe*(qe.x + ve.x) + pa*(qa.x + va.x);
  o.y = hp.y + iv.y + pe*(qe.y + ve.y) + pa*(qa.y + va.y);
  o.z = hp.z + iv.z + pe*(qe.z + ve.z) + pa*(qa.z + va.z);
  o.w = hp.w + iv.w + pe*(qe.w + ve.w) + pa*(qa.w + va.w);
  o.x = fmaxf(o.x, 0.f); o.y = fmaxf(o.y, 0.f);
  o.z = fmaxf(o.z, 0.f); o.w = fmaxf(o.w, 0.f);
  *(float4*)&out[base] = o;
}

extern "C" void kernel_launch(void* const* d_in, const int* in_sizes, int n_in,
                              void* d_out, int out_size, void* d_ws, size_t ws_size,
                              hipStream_t stream) {
  const float* inp  = (const float*)d_in[0];
  const float* emo  = (const float*)d_in[1];
  const float* bef  = (const float*)d_in[2];
  const float* aft  = (const float*)d_in[3];
  const float* ei   = (const float*)d_in[4];
  const float* eo   = (const float*)d_in[5];
  const float* ii   = (const float*)d_in[6];
  const float* io   = (const float*)d_in[7];
  const float* W    = (const float*)d_in[8];
  const float* a    = (const float*)d_in[9];
  const float* cskW = (const float*)d_in[10];
  const float* cskb = (const float*)d_in[11];
  const float* eW   = (const float*)d_in[12];
  const float* eb   = (const float*)d_in[13];
  const float* aW   = (const float*)d_in[14];
  const float* ab   = (const float*)d_in[15];
  const int*   cl   = (const int*)d_in[16];
  const int*   intra= (const int*)d_in[17];
  float* ws  = (float*)d_ws;
  float* out = (float*)d_out;
  ushort* bt = (ushort*)(ws + OFF_BT);

  k_bt<<<dim3(16, 5), 256, 0, stream>>>(W, eW, aW, bt);
  k_qpart<<<dim3(16, 2), 256, 0, stream>>>(inp, emo, eW, aW, cl, ws);
  k_mgemmh<<<dim3(128, 2), 256, 0, stream>>>(inp, bt, ws + OFF_H);
  k_qfinish<<<dim3(B, 2), 256, 0, stream>>>(eb, ab, cskb, a, ws);
  k_u<<<2048, 256, 0, stream>>>(ei, eo, ii, io, cl, intra, ws);
  k_rowdots<<<dim3(64, 17), 256, 0, stream>>>(eW, aW, cskW, a, ws);
  k_s12<<<512, 256, 0, stream>>>(bef, aft, a, ws);
  k_cntj<<<dim3(8, B), 256, 0, stream>>>(ws);
  k_scan<<<dim3(B, 2), 1024, 0, stream>>>(ws);
  k_rank<<<dim3(8, B), 256, 0, stream>>>(ws);
  k_p1<<<dim3(32, B), 256, 0, stream>>>(ws);
  k_p3<<<dim3(32, B), 256, 0, stream>>>(ws);
  k_hprime2<<<dim3(256, B), 256, 0, stream>>>(ws);
  k_mgemm2<<<dim3(128, 2, 2), 256, 0, stream>>>(ws + OFF_HP, bt, ws);
  k_softmax<<<B, 1024, 0, stream>>>(ws, out);
  k_final<<<2048, 256, 0, stream>>>(inp, ws, out);
}

// Round 6
// 140.033 us; speedup vs baseline: 1.2855x; 1.2855x over previous
//
#include <hip/hip_runtime.h>
#include <math.h>

// ---------------------------------------------------------------------------
// Problem: B=4, N=2048, D=256.
// Key exact simplifications:
//  * intra+inter == 1  -> attention = softmax_j(leaky_relu(s1_i + s2_j)), no masks
//  * rank-1 + monotone -> h_prime via sorted-s2 prefix sums (O(N D), exact)
//  * evt / k_base / w_i / w_o folded into matvecs; only 3 big GEMMs remain
// R1: k_hprime -> k_rank + k_hprime2 (was 73us latency-bound).
// R2: k_setup -> k_qpart + k_qfinish + k_rowdots (was 64us, 4 blocks).
// R3: f32 VALU GEMMs -> bf16 MFMA 16x16x32 (3x40us -> ~8us each).
// R4: k_logits fused into k_hprime2; k_p2 folded into k_p3; tail GEMMs merged.
//     k_cntj rank-by-count FAILED: 52us (1 wave/SIMD, no ILP, VGPR=8).
// R5: k_cntj -> k_cnt2 (512 blocks: 8 j-blk x 16 k-chunk x 4 b, unrolled
//     32 independent LDS reads/thread) + k_cntfin (sum 16 partials, scatter).
// ---------------------------------------------------------------------------

namespace {
constexpr int B = 4, N = 2048, D = 256;
constexpr float ALPHA = 0.2f;
constexpr float INVS  = 0.0625f;   // 1/sqrt(256)

// ws offsets (float elements)
constexpr size_t OFF_H     = 0;                       // (B,N,D)
constexpr size_t OFF_HP    = 2097152;                 // h_prime
constexpr size_t OFF_UE    = 4194304;                 // u_emo
constexpr size_t OFF_UA    = 6291456;                 // u_act
constexpr size_t OFF_PPOS  = 8388608;                 // (B,N+1,D) prefix, later Ve
constexpr size_t OFF_PNEG  = 10486784;                // (B,N+1,D) prefix, later Va
constexpr size_t OFF_VE    = OFF_PPOS;
constexpr size_t OFF_VA    = OFF_PNEG;
constexpr size_t OFF_S1    = 12584960;                // (B,N)
constexpr size_t OFF_S2    = OFF_S1 + 8192;
constexpr size_t OFF_SV    = OFF_S2 + 8192;           // sorted s2
constexpr size_t OFF_SIDX  = OFF_SV + 8192;           // permutation (int)
constexpr size_t OFF_WP    = OFF_SIDX + 8192;         // e^{s2} sorted
constexpr size_t OFF_WN    = OFF_WP + 8192;           // e^{a s2} sorted
constexpr size_t OFF_ZP    = OFF_WN + 8192;           // (B,N+1) scalar prefix
constexpr size_t OFF_ZN    = OFF_ZP + 8196;
constexpr size_t OFF_PARTP = OFF_ZN + 8196;           // (B,32,D) chunk partials
constexpr size_t OFF_PARTN = OFF_PARTP + 32768;
constexpr size_t OFF_LE    = OFF_PARTN + 32768;       // emo logits
constexpr size_t OFF_LA    = OFF_LE + 8192;           // act logits
constexpr size_t OFF_SET   = OFF_LA + 8192;
constexpr size_t KQE = OFF_SET + 0;      // kW@q per batch (B,256)
constexpr size_t WQE = OFF_SET + 1024;
constexpr size_t KQA = OFF_SET + 2048;
constexpr size_t WQA = OFF_SET + 3072;
constexpr size_t QCE = OFF_SET + 4096;   // q + vb + wb
constexpr size_t QCA = OFF_SET + 5120;
constexpr size_t CA2 = OFF_SET + 6144;   // csk_W @ a2 (256)
constexpr size_t CEc = OFF_SET + 6400;   // q.(kb+wb) per batch
constexpr size_t CAc = OFF_SET + 6404;
constexpr size_t C2c = OFF_SET + 6408;   // 2*csk_b.a2
constexpr size_t OFF_RNK   = OFF_SET + 8192;          // (B,N) int
constexpr size_t OFF_C0    = OFF_RNK + 8192;          // ep/den
constexpr size_t OFF_C1    = OFF_C0 + 8192;           // en/den
constexpr size_t OFF_PARTQ = OFF_C1 + 8192;           // [m2][c16][b4][256]
constexpr size_t OFF_QE    = OFF_PARTQ + 32768;       // (B,256)
constexpr size_t OFF_QA    = OFF_QE + 1024;
constexpr size_t OFF_BT    = OFF_QA + 1024;           // 5 x 256x256 bf16 B^T (ushort)
constexpr size_t OFF_PCNT  = OFF_BT + 163840;         // (B,16,N) int partial counts
}

typedef __attribute__((ext_vector_type(8))) short bf16x8;
typedef __attribute__((ext_vector_type(4))) float f32x4;

__device__ inline float wave_sum(float v) {
#pragma unroll
  for (int off = 32; off > 0; off >>= 1) v += __shfl_xor(v, off, 64);
  return v;
}

__device__ inline ushort f2bf(float x) {
  union { float f; uint u; } v; v.f = x;
  return (ushort)((v.u + 0x7FFFu + ((v.u >> 16) & 1u)) >> 16);
}
__device__ inline uint pk2bf(float a, float b) {
  return (uint)f2bf(a) | ((uint)f2bf(b) << 16);
}

// --- R3: transpose + convert the 5 weight matrices (256x256) ------------------
__global__ __launch_bounds__(256) void k_bt(
    const float* __restrict__ Wm, const float* __restrict__ eW,
    const float* __restrict__ aW, ushort* __restrict__ bt)
{
  int m = blockIdx.y;
  const float* src = (m == 0) ? Wm : (m == 1) ? eW + 3*65536 : (m == 2) ? eW
                   : (m == 3) ? aW + 3*65536 : aW;
  ushort* dst = bt + (size_t)m*65536;
  int k0 = (blockIdx.x >> 2)*64, n0 = (blockIdx.x & 3)*64;
  __shared__ float tile[64][65];
  int r = threadIdx.x >> 2, c0 = (threadIdx.x & 3)*16;
#pragma unroll
  for (int cc = 0; cc < 16; cc += 4)
    *(float4*)&tile[r][c0+cc] = *(const float4*)&src[(size_t)(k0+r)*256 + n0 + c0 + cc];
  __syncthreads();
  int n = threadIdx.x >> 2, kq = (threadIdx.x & 3)*16;
  uint4 o0, o1;
  o0.x = pk2bf(tile[kq+ 0][n], tile[kq+ 1][n]);
  o0.y = pk2bf(tile[kq+ 2][n], tile[kq+ 3][n]);
  o0.z = pk2bf(tile[kq+ 4][n], tile[kq+ 5][n]);
  o0.w = pk2bf(tile[kq+ 6][n], tile[kq+ 7][n]);
  o1.x = pk2bf(tile[kq+ 8][n], tile[kq+ 9][n]);
  o1.y = pk2bf(tile[kq+10][n], tile[kq+11][n]);
  o1.z = pk2bf(tile[kq+12][n], tile[kq+13][n]);
  o1.w = pk2bf(tile[kq+14][n], tile[kq+15][n]);
  *(uint4*)&dst[(size_t)(n0+n)*256 + k0 + kq]     = o0;
  *(uint4*)&dst[(size_t)(n0+n)*256 + k0 + kq + 8] = o1;
}

// --- R4: MFMA body with inline f32->bf16 A staging ----------------------------
__device__ __forceinline__ void mgemm_body(ushort* As,
    const float* __restrict__ A1, const ushort* __restrict__ B1,
    const float* __restrict__ A2, const ushort* __restrict__ B2,
    float* __restrict__ C)
{
  const int t = threadIdx.x;
  const int lane = t & 63, w = t >> 6;
  const int wm = w >> 1, wn = w & 1;
  const int laneN = lane & 15, kg = lane >> 4;
  const int m0 = blockIdx.x * 64, n0 = blockIdx.y * 128;
  const int srow = t >> 2, sq = t & 3;
  f32x4 acc[2][4] = {};
  for (int src = 0; src < 2; ++src) {
    const float* A = src ? A2 : A1;
    const ushort* Bt = src ? B2 : B1;
    if (!A) break;
    for (int k0 = 0; k0 < 256; k0 += 32) {
      __syncthreads();
      float4 f0 = *(const float4*)&A[(size_t)(m0 + srow)*256 + k0 + sq*8];
      float4 f1 = *(const float4*)&A[(size_t)(m0 + srow)*256 + k0 + sq*8 + 4];
      uint4 o;
      o.x = pk2bf(f0.x, f0.y); o.y = pk2bf(f0.z, f0.w);
      o.z = pk2bf(f1.x, f1.y); o.w = pk2bf(f1.z, f1.w);
      *(uint4*)&As[srow*40 + sq*8] = o;
      __syncthreads();
      bf16x8 bf[4];
#pragma unroll
      for (int j = 0; j < 4; ++j)
        bf[j] = *(const bf16x8*)&Bt[(size_t)(n0 + wn*64 + j*16 + laneN)*256 + k0 + kg*8];
#pragma unroll
      for (int i = 0; i < 2; ++i) {
        bf16x8 af = *(const bf16x8*)&As[(wm*32 + i*16 + laneN)*40 + kg*8];
#pragma unroll
        for (int j = 0; j < 4; ++j)
          acc[i][j] = __builtin_amdgcn_mfma_f32_16x16x32_bf16(af, bf[j], acc[i][j], 0, 0, 0);
      }
    }
  }
#pragma unroll
  for (int i = 0; i < 2; ++i)
#pragma unroll
    for (int j = 0; j < 4; ++j)
#pragma unroll
      for (int r = 0; r < 4; ++r)
        C[(size_t)(m0 + wm*32 + i*16 + kg*4 + r)*256 + n0 + wn*64 + j*16 + laneN]
            = acc[i][j][r];
}

__global__ __launch_bounds__(256) void k_mgemmh(
    const float* __restrict__ A1, const ushort* __restrict__ bt,
    float* __restrict__ C)
{
  __shared__ ushort As[64*40];
  mgemm_body(As, A1, bt, nullptr, nullptr, C);
}

// z=0: Ve = hp@eW_v + ue@eW_w ; z=1: Va = hp@aW_v + ua@aW_w
__global__ __launch_bounds__(256) void k_mgemm2(
    const float* __restrict__ hp, const ushort* __restrict__ bt,
    float* __restrict__ ws)
{
  __shared__ ushort As[64*40];
  int z = blockIdx.z;
  const float* A2 = ws + (z ? OFF_UA : OFF_UE);
  const ushort* B1 = bt + (size_t)(z ? 3 : 1)*65536;
  const ushort* B2 = bt + (size_t)(z ? 4 : 2)*65536;
  float* C = ws + (z ? OFF_VA : OFF_VE);
  mgemm_body(As, hp, B1, A2, B2, C);
}

// --- R2: split-k partials of q = x @ qW ---------------------------------------
__global__ __launch_bounds__(256) void k_qpart(
    const float* __restrict__ inp, const float* __restrict__ emo,
    const float* __restrict__ eW, const float* __restrict__ aW,
    const int* __restrict__ cl, float* __restrict__ ws)
{
  int c = blockIdx.x;          // k-chunk 0..15
  int m = blockIdx.y;          // 0=emo, 1=act
  int d = threadIdx.x;
  __shared__ float xs[B][16];
  if (d < 64) {
    int b = d >> 4, kk = d & 15;
    int t = cl[b] - 1;
    size_t idx = ((size_t)b*N + t)*D + c*16 + kk;
    float v = inp[idx];
    if (m == 0) v += emo[idx];
    xs[b][kk] = v;
  }
  __syncthreads();
  const float* Wq = (m ? aW : eW) + (size_t)D*D;   // lin_W[1]
  float acc0 = 0.f, acc1 = 0.f, acc2 = 0.f, acc3 = 0.f;
#pragma unroll
  for (int kk = 0; kk < 16; ++kk) {
    int k = c*16 + kk;
    float w = Wq[(size_t)k*D + d];
    acc0 += xs[0][kk]*w; acc1 += xs[1][kk]*w;
    acc2 += xs[2][kk]*w; acc3 += xs[3][kk]*w;
  }
  size_t base = OFF_PARTQ + ((size_t)(m*16 + c)*4)*256 + d;
  ws[base + 0*256] = acc0; ws[base + 1*256] = acc1;
  ws[base + 2*256] = acc2; ws[base + 3*256] = acc3;
}

// --- R2: q = sum partials + qb; qc; scalar dots --------------------------------
__global__ __launch_bounds__(256) void k_qfinish(
    const float* __restrict__ eb, const float* __restrict__ ab,
    const float* __restrict__ cskb, const float* __restrict__ a,
    float* __restrict__ ws)
{
  int b = blockIdx.x, m = blockIdx.y, d = threadIdx.x;
  __shared__ float red[D];
  const float* bias = m ? ab : eb;
  float q = bias[D + d];
#pragma unroll
  for (int c = 0; c < 16; ++c)
    q += ws[OFF_PARTQ + ((size_t)(m*16 + c)*4 + b)*256 + d];
  ws[(m ? OFF_QA : OFF_QE) + (size_t)b*D + d] = q;
  ws[(m ? QCA : QCE) + (size_t)b*D + d] = q + bias[3*D + d] + bias[0*D + d];
  red[d] = q * (bias[2*D + d] + bias[0*D + d]);
  __syncthreads();
  for (int s = 128; s > 0; s >>= 1) { if (d < s) red[d] += red[d+s]; __syncthreads(); }
  if (d == 0) ws[(m ? CAc : CEc) + b] = red[0];
  if (m == 1 && b == 0) {
    __syncthreads();
    red[d] = cskb[d] * a[D + d];
    __syncthreads();
    for (int s = 128; s > 0; s >>= 1) { if (d < s) red[d] += red[d+s]; __syncthreads(); }
    if (d == 0) ws[C2c] = 2.0f * red[0];
  }
}

// --- R2: 17 row-major matvecs, wave-per-row, coalesced -------------------------
__global__ __launch_bounds__(256) void k_rowdots(
    const float* __restrict__ eW, const float* __restrict__ aW,
    const float* __restrict__ cskW, const float* __restrict__ a,
    float* __restrict__ ws)
{
  int job = blockIdx.y;
  int wid = threadIdx.x >> 6, lane = threadIdx.x & 63;
  int row = blockIdx.x*4 + wid;
  __shared__ float vec[D];
  const float* M; size_t outo;
  if (job < 16) {
    int b = job >> 2, m = (job >> 1) & 1, which = job & 1;
    const float* base = m ? aW : eW;
    M = base + (which ? 0 : (size_t)2*D*D);          // wW : kW
    if (threadIdx.x < D)
      vec[threadIdx.x] = ws[(m ? OFF_QA : OFF_QE) + (size_t)b*D + threadIdx.x];
    outo = (which ? (m ? WQA : WQE) : (m ? KQA : KQE)) + (size_t)b*D;
  } else {
    M = cskW;
    if (threadIdx.x < D) vec[threadIdx.x] = a[D + threadIdx.x];
    outo = CA2;
  }
  __syncthreads();
  float4 w = *reinterpret_cast<const float4*>(&M[(size_t)row*D + lane*4]);
  float s = w.x*vec[lane*4] + w.y*vec[lane*4+1] + w.z*vec[lane*4+2] + w.w*vec[lane*4+3];
  s = wave_sum(s);
  if (lane == 0) ws[outo + row] = s;
}

// --- u = tim*icsk + (1-tim)*ocsk for both measures ----------------------------
__global__ __launch_bounds__(256) void k_u(
    const float* __restrict__ ei, const float* __restrict__ eo,
    const float* __restrict__ ai, const float* __restrict__ ao,
    const int* __restrict__ cl, const int* __restrict__ intra,
    float* __restrict__ ws)
{
  size_t g = (size_t)blockIdx.x*256 + threadIdx.x;
  size_t base = g << 2;
  int b = (int)(base >> 19);              // N*D = 2^19
  int n = (int)((base >> 8) & (N - 1));
  int t = cl[b] - 1;
  float tm = (float)intra[(size_t)b*N*N + (size_t)t*N + n];
  float om = 1.0f - tm;
  float4 vei = *(const float4*)&ei[base];
  float4 veo = *(const float4*)&eo[base];
  float4 vai = *(const float4*)&ai[base];
  float4 vao = *(const float4*)&ao[base];
  float4 ue, ua;
  ue.x = tm*vei.x + om*veo.x; ue.y = tm*vei.y + om*veo.y;
  ue.z = tm*vei.z + om*veo.z; ue.w = tm*vei.w + om*veo.w;
  ua.x = tm*vai.x + om*vao.x; ua.y = tm*vai.y + om*vao.y;
  ua.z = tm*vai.z + om*vao.z; ua.w = tm*vai.w + om*vao.w;
  *(float4*)&ws[OFF_UE + base] = ue;
  *(float4*)&ws[OFF_UA + base] = ua;
}

// --- s1 = h.a1 ; s2 = h.a2 + (bef+aft).ca2 + c2 -------------------------------
__global__ __launch_bounds__(256) void k_s12(
    const float* __restrict__ bef, const float* __restrict__ aft,
    const float* __restrict__ a, float* __restrict__ ws)
{
  int wid  = (int)(((size_t)blockIdx.x*256 + threadIdx.x) >> 6);
  int lane = threadIdx.x & 63;
  int d0 = lane << 2;
  float4 a1 = *(const float4*)&a[d0];
  float4 a2 = *(const float4*)&a[D + d0];
  float4 cv = *(const float4*)&ws[CA2 + d0];
  float c2  = ws[C2c];
  for (int rr = 0; rr < 4; ++rr) {
    int row = wid*4 + rr;
    float4 h4 = *(const float4*)&ws[OFF_H + (size_t)row*D + d0];
    float4 b4 = *(const float4*)&bef[(size_t)row*D + d0];
    float4 f4 = *(const float4*)&aft[(size_t)row*D + d0];
    float s1 = h4.x*a1.x + h4.y*a1.y + h4.z*a1.z + h4.w*a1.w;
    float s2 = h4.x*a2.x + h4.y*a2.y + h4.z*a2.z + h4.w*a2.w
             + (b4.x+f4.x)*cv.x + (b4.y+f4.y)*cv.y
             + (b4.z+f4.z)*cv.z + (b4.w+f4.w)*cv.w;
    s1 = wave_sum(s1); s2 = wave_sum(s2);
    if (lane == 0) { ws[OFF_S1 + row] = s1; ws[OFF_S2 + row] = s2 + c2; }
  }
}

// --- R5: partial rank counts over 128-value k-chunks ---------------------------
__global__ __launch_bounds__(256) void k_cnt2(float* __restrict__ ws)
{
  int jb = blockIdx.x;          // 0..7
  int kb = blockIdx.y;          // 0..15
  int b  = blockIdx.z;
  int tid = threadIdx.x;
  __shared__ float ck[128];
  if (tid < 32)
    *(float4*)&ck[tid*4] = *(const float4*)&ws[OFF_S2 + (size_t)b*N + kb*128 + tid*4];
  __syncthreads();
  int j = jb*256 + tid;
  float v = ws[OFF_S2 + (size_t)b*N + j];
  int kg = kb*128;
  int cnt = 0;
#pragma unroll
  for (int k = 0; k < 128; k += 16) {
    float4 u0 = *(const float4*)&ck[k];
    float4 u1 = *(const float4*)&ck[k+4];
    float4 u2 = *(const float4*)&ck[k+8];
    float4 u3 = *(const float4*)&ck[k+12];
    cnt += (u0.x < v) || (u0.x == v && (kg+k+ 0) < j);
    cnt += (u0.y < v) || (u0.y == v && (kg+k+ 1) < j);
    cnt += (u0.z < v) || (u0.z == v && (kg+k+ 2) < j);
    cnt += (u0.w < v) || (u0.w == v && (kg+k+ 3) < j);
    cnt += (u1.x < v) || (u1.x == v && (kg+k+ 4) < j);
    cnt += (u1.y < v) || (u1.y == v && (kg+k+ 5) < j);
    cnt += (u1.z < v) || (u1.z == v && (kg+k+ 6) < j);
    cnt += (u1.w < v) || (u1.w == v && (kg+k+ 7) < j);
    cnt += (u2.x < v) || (u2.x == v && (kg+k+ 8) < j);
    cnt += (u2.y < v) || (u2.y == v && (kg+k+ 9) < j);
    cnt += (u2.z < v) || (u2.z == v && (kg+k+10) < j);
    cnt += (u2.w < v) || (u2.w == v && (kg+k+11) < j);
    cnt += (u3.x < v) || (u3.x == v && (kg+k+12) < j);
    cnt += (u3.y < v) || (u3.y == v && (kg+k+13) < j);
    cnt += (u3.z < v) || (u3.z == v && (kg+k+14) < j);
    cnt += (u3.w < v) || (u3.w == v && (kg+k+15) < j);
  }
  ((int*)ws)[OFF_PCNT + ((size_t)(b*16 + kb))*N + j] = cnt;
}

// --- R5: sum partial counts, scatter sorted SV/SIDX/WP/WN ----------------------
__global__ __launch_bounds__(256) void k_cntfin(float* __restrict__ ws)
{
  int b = blockIdx.y;
  int j = blockIdx.x*256 + threadIdx.x;
  int cnt = 0;
#pragma unroll
  for (int kb = 0; kb < 16; ++kb)
    cnt += ((const int*)ws)[OFF_PCNT + ((size_t)(b*16 + kb))*N + j];
  float v = ws[OFF_S2 + (size_t)b*N + j];
  size_t o = (size_t)b*N + cnt;
  ws[OFF_SV + o] = v;
  ((int*)ws)[OFF_SIDX + o] = j;
  ws[OFF_WP + o] = expf(v);
  ws[OFF_WN + o] = expf(ALPHA*v);
}

// --- R4: scalar prefix sums of sorted WP/WN -> ZP/ZN ---------------------------
__global__ __launch_bounds__(1024) void k_scan(float* __restrict__ ws)
{
  int b = blockIdx.x, m = blockIdx.y, t = threadIdx.x;
  const float* src = ws + (m ? OFF_WN : OFF_WP) + (size_t)b*N;
  float* dst = ws + (m ? OFF_ZN : OFF_ZP) + (size_t)b*(N+1);
  __shared__ float buf[N];
  buf[t] = src[t]; buf[t + 1024] = src[t + 1024];
  __syncthreads();
  for (int off = 1; off < N; off <<= 1) {
    float v0 = (t >= off)        ? buf[t - off]        : 0.f;
    float v1 = (t + 1024 >= off) ? buf[t + 1024 - off] : 0.f;
    __syncthreads();
    buf[t] += v0; buf[t + 1024] += v1;
    __syncthreads();
  }
  if (t == 0) dst[0] = 0.f;
  dst[t + 1]    = buf[t];
  dst[t + 1025] = buf[t + 1024];
}

// --- R1: per-row rank + folded softmax coefficients ----------------------------
__global__ __launch_bounds__(256) void k_rank(float* __restrict__ ws)
{
  int b = blockIdx.y;
  int i = blockIdx.x * 256 + threadIdx.x;
  __shared__ float sv[N];
  for (int r = threadIdx.x; r < N; r += 256) sv[r] = ws[OFF_SV + (size_t)b*N + r];
  __syncthreads();
  float s1i = ws[OFF_S1 + (size_t)b*N + i];
  float th = -s1i;
  int lo = 0, hi = N;
  while (lo < hi) { int mid = (lo + hi) >> 1; if (sv[mid] <= th) lo = mid + 1; else hi = mid; }
  int r = lo;
  float ep = expf(s1i), en = expf(ALPHA*s1i);
  float zp  = ws[OFF_ZP + (size_t)b*(N+1) + r];
  float zn  = ws[OFF_ZN + (size_t)b*(N+1) + r];
  float zpT = ws[OFF_ZP + (size_t)b*(N+1) + N];
  float den = ep*(zpT - zp) + en*zn;
  ((int*)ws)[OFF_RNK + (size_t)b*N + i] = r;
  ws[OFF_C0 + (size_t)b*N + i] = ep/den;
  ws[OFF_C1 + (size_t)b*N + i] = en/den;
}

// --- vector partials over sorted order ----------------------------------------
__global__ __launch_bounds__(256) void k_p1(float* __restrict__ ws)
{
  int c = blockIdx.x, b = blockIdx.y, d = threadIdx.x;
  const int*   sidx = (const int*)ws + OFF_SIDX + (size_t)b*N;
  const float* wp = ws + OFF_WP + (size_t)b*N;
  const float* wn = ws + OFF_WN + (size_t)b*N;
  const float* h  = ws + OFF_H + (size_t)b*N*D;
  float ap = 0.f, an = 0.f;
  for (int r = c*64; r < c*64 + 64; ++r) {
    float hv = h[(size_t)sidx[r]*D + d];
    ap += wp[r]*hv; an += wn[r]*hv;
  }
  ws[OFF_PARTP + ((size_t)b*32 + c)*D + d] = ap;
  ws[OFF_PARTN + ((size_t)b*32 + c)*D + d] = an;
}

// --- R4: p3 computes its own chunk offset (k_p2 removed) -----------------------
__global__ __launch_bounds__(256) void k_p3(float* __restrict__ ws)
{
  int c = blockIdx.x, b = blockIdx.y, d = threadIdx.x;
  const int*   sidx = (const int*)ws + OFF_SIDX + (size_t)b*N;
  const float* wp = ws + OFF_WP + (size_t)b*N;
  const float* wn = ws + OFF_WN + (size_t)b*N;
  const float* h  = ws + OFF_H + (size_t)b*N*D;
  float ap = 0.f, an = 0.f;
  for (int c2 = 0; c2 < c; ++c2) {
    ap += ws[OFF_PARTP + ((size_t)b*32 + c2)*D + d];
    an += ws[OFF_PARTN + ((size_t)b*32 + c2)*D + d];
  }
  for (int r = c*64; r < c*64 + 64; ++r) {
    ws[OFF_PPOS + ((size_t)b*(N+1) + r)*D + d] = ap;
    ws[OFF_PNEG + ((size_t)b*(N+1) + r)*D + d] = an;
    float hv = h[(size_t)sidx[r]*D + d];
    ap += wp[r]*hv; an += wn[r]*hv;
  }
  if (c == 31) {
    ws[OFF_PPOS + ((size_t)b*(N+1) + N)*D + d] = ap;
    ws[OFF_PNEG + ((size_t)b*(N+1) + N)*D + d] = an;
  }
}

// --- R4: h_prime gather + fused logits (k_logits removed) ----------------------
__global__ __launch_bounds__(256) void k_hprime2(float* __restrict__ ws)
{
  int b = blockIdx.y, d = threadIdx.x;
  int i0 = blockIdx.x * 8;
  float totp = ws[OFF_PPOS + ((size_t)b*(N+1) + N)*D + d];
  float kqe = ws[KQE + (size_t)b*D + d], wqe = ws[WQE + (size_t)b*D + d];
  float kqa = ws[KQA + (size_t)b*D + d], wqa = ws[WQA + (size_t)b*D + d];
  float se[8], sa[8];
#pragma unroll
  for (int ii = 0; ii < 8; ++ii) {
    int i = i0 + ii;
    int   r  = ((const int*)ws)[OFF_RNK + (size_t)b*N + i];
    float c0 = ws[OFF_C0 + (size_t)b*N + i];
    float c1 = ws[OFF_C1 + (size_t)b*N + i];
    float pp = ws[OFF_PPOS + ((size_t)b*(N+1) + r)*D + d];
    float pn = ws[OFF_PNEG + ((size_t)b*(N+1) + r)*D + d];
    float v = c0*(totp - pp) + c1*pn;
    size_t base = ((size_t)b*N + i)*D + d;
    ws[OFF_HP + base] = v;
    float ue = ws[OFF_UE + base], ua = ws[OFF_UA + base];
    se[ii] = v*kqe + ue*wqe;
    sa[ii] = v*kqa + ua*wqa;
  }
  __shared__ float lred[16][4];
  int w = d >> 6, lane = d & 63;
#pragma unroll
  for (int ii = 0; ii < 8; ++ii) {
    float s = wave_sum(se[ii]);
    if (lane == 0) lred[ii][w] = s;
    s = wave_sum(sa[ii]);
    if (lane == 0) lred[8 + ii][w] = s;
  }
  __syncthreads();
  if (d < 16) {
    float s = lred[d][0] + lred[d][1] + lred[d][2] + lred[d][3];
    size_t row = (size_t)b*N + i0 + (d & 7);
    if (d < 8) ws[OFF_LE + row] = (s + ws[CEc + b]) * INVS;
    else       ws[OFF_LA + row] = (s + ws[CAc + b]) * INVS;
  }
}

// --- probs softmax over N, writes directly to d_out -----------------------------
__global__ __launch_bounds__(1024) void k_softmax(const float* __restrict__ ws,
                                                  float* __restrict__ out)
{
  int b = blockIdx.x, t = threadIdx.x;
  __shared__ float red[1024];
  for (int m = 0; m < 2; ++m) {
    const float* l = ws + (m ? OFF_LA : OFF_LE) + (size_t)b*N;
    float* p = out + (size_t)B*N*D + (size_t)m*B*N + (size_t)b*N;
    float v0 = l[t], v1 = l[t + 1024];
    red[t] = fmaxf(v0, v1);
    __syncthreads();
    for (int s = 512; s > 0; s >>= 1) { if (t < s) red[t] = fmaxf(red[t], red[t+s]); __syncthreads(); }
    float mx = red[0];
    __syncthreads();
    float e0 = expf(v0 - mx), e1 = expf(v1 - mx);
    red[t] = e0 + e1;
    __syncthreads();
    for (int s = 512; s > 0; s >>= 1) { if (t < s) red[t] += red[t+s]; __syncthreads(); }
    float inv = 1.0f / red[0];
    __syncthreads();
    p[t] = e0 * inv; p[t + 1024] = e1 * inv;
    __syncthreads();
  }
}

// --- final: out = relu(h' + inp + pe*(qce+Ve) + pa*(qca+Va)) --------------------
__global__ __launch_bounds__(256) void k_final(
    const float* __restrict__ inp, const float* __restrict__ ws,
    float* __restrict__ out)
{
  size_t g = (size_t)blockIdx.x*256 + threadIdx.x;
  size_t base = g << 2;
  int b  = (int)(base >> 19);
  int n  = (int)((base >> 8) & (N - 1));
  int d0 = (int)(base & (D - 1));
  float pe = out[(size_t)B*N*D + (size_t)b*N + n];
  float pa = out[(size_t)B*N*D + (size_t)B*N + (size_t)b*N + n];
  float4 hp = *(const float4*)&ws[OFF_HP + base];
  float4 iv = *(const float4*)&inp[base];
  float4 ve = *(const float4*)&ws[OFF_VE + base];
  float4 va = *(const float4*)&ws[OFF_VA + base];
  float4 qe = *(const float4*)&ws[QCE + (size_t)b*D + d0];
  float4 qa = *(const float4*)&ws[QCA + (size_t)b*D + d0];
  float4 o;
  o.x = hp.x + iv.x + pe*(qe.x + ve.x) + pa*(qa.x + va.x);
  o.y = hp.y + iv.y + pe*(qe.y + ve.y) + pa*(qa.y + va.y);
  o.z = hp.z + iv.z + pe*(qe.z + ve.z) + pa*(qa.z + va.z);
  o.w = hp.w + iv.w + pe*(qe.w + ve.w) + pa*(qa.w + va.w);
  o.x = fmaxf(o.x, 0.f); o.y = fmaxf(o.y, 0.f);
  o.z = fmaxf(o.z, 0.f); o.w = fmaxf(o.w, 0.f);
  *(float4*)&out[base] = o;
}

extern "C" void kernel_launch(void* const* d_in, const int* in_sizes, int n_in,
                              void* d_out, int out_size, void* d_ws, size_t ws_size,
                              hipStream_t stream) {
  const float* inp  = (const float*)d_in[0];
  const float* emo  = (const float*)d_in[1];
  const float* bef  = (const float*)d_in[2];
  const float* aft  = (const float*)d_in[3];
  const float* ei   = (const float*)d_in[4];
  const float* eo   = (const float*)d_in[5];
  const float* ii   = (const float*)d_in[6];
  const float* io   = (const float*)d_in[7];
  const float* W    = (const float*)d_in[8];
  const float* a    = (const float*)d_in[9];
  const float* cskW = (const float*)d_in[10];
  const float* cskb = (const float*)d_in[11];
  const float* eW   = (const float*)d_in[12];
  const float* eb   = (const float*)d_in[13];
  const float* aW   = (const float*)d_in[14];
  const float* ab   = (const float*)d_in[15];
  const int*   cl   = (const int*)d_in[16];
  const int*   intra= (const int*)d_in[17];
  float* ws  = (float*)d_ws;
  float* out = (float*)d_out;
  ushort* bt = (ushort*)(ws + OFF_BT);

  k_bt<<<dim3(16, 5), 256, 0, stream>>>(W, eW, aW, bt);
  k_qpart<<<dim3(16, 2), 256, 0, stream>>>(inp, emo, eW, aW, cl, ws);
  k_mgemmh<<<dim3(128, 2), 256, 0, stream>>>(inp, bt, ws + OFF_H);
  k_qfinish<<<dim3(B, 2), 256, 0, stream>>>(eb, ab, cskb, a, ws);
  k_u<<<2048, 256, 0, stream>>>(ei, eo, ii, io, cl, intra, ws);
  k_rowdots<<<dim3(64, 17), 256, 0, stream>>>(eW, aW, cskW, a, ws);
  k_s12<<<512, 256, 0, stream>>>(bef, aft, a, ws);
  k_cnt2<<<dim3(8, 16, B), 256, 0, stream>>>(ws);
  k_cntfin<<<dim3(8, B), 256, 0, stream>>>(ws);
  k_scan<<<dim3(B, 2), 1024, 0, stream>>>(ws);
  k_rank<<<dim3(8, B), 256, 0, stream>>>(ws);
  k_p1<<<dim3(32, B), 256, 0, stream>>>(ws);
  k_p3<<<dim3(32, B), 256, 0, stream>>>(ws);
  k_hprime2<<<dim3(256, B), 256, 0, stream>>>(ws);
  k_mgemm2<<<dim3(128, 2, 2), 256, 0, stream>>>(ws + OFF_HP, bt, ws);
  k_softmax<<<B, 1024, 0, stream>>>(ws, out);
  k_final<<<2048, 256, 0, stream>>>(inp, ws, out);
}